// Round 7
// baseline (187.162 us; speedup 1.0000x reference)
//
#include <hip/hip_runtime.h>
#include <math.h>

#define Bn 8
#define Hd 128
#define Ld 8192
#define Pd 256
#define LC 32
#define NC 256  // Ld / LC

typedef __attribute__((ext_vector_type(8))) short bf16x8;
typedef __attribute__((ext_vector_type(4))) float f32x4;
#define MFMA16(a, b, c) __builtin_amdgcn_mfma_f32_16x16x32_bf16(a, b, c, 0, 0, 0)

__device__ __forceinline__ unsigned short f2bf(float f) {
  unsigned u = __float_as_uint(f);
  u = u + 0x7fffu + ((u >> 16) & 1u);  // round-to-nearest-even
  return (unsigned short)(u >> 16);
}

#if __has_builtin(__builtin_amdgcn_cvt_pk_bf16_f32)
typedef __attribute__((ext_vector_type(2))) __bf16 v2bf_t;
__device__ __forceinline__ unsigned pack2(float a, float b) {
  v2bf_t r = __builtin_amdgcn_cvt_pk_bf16_f32(a, b);  // low = a, high = b
  unsigned u;
  __builtin_memcpy(&u, &r, 4);
  return u;
}
#else
__device__ __forceinline__ unsigned pack2(float a, float b) {
  return (unsigned)f2bf(a) | ((unsigned)f2bf(b) << 16);
}
#endif

__device__ __forceinline__ float bflo(unsigned v) { return __uint_as_float(v << 16); }
__device__ __forceinline__ float bfhi(unsigned v) { return __uint_as_float(v & 0xffff0000u); }

// bu column swizzle: bijective 5-bit perm of p&31 -> 2-way-max banks on both
// C-frag writes (lanes vary q,ln) and per-p scan reads (lanes vary p).
__device__ __forceinline__ int bperm(int p) {
  return ((p & 4) << 2) | ((p & 16) >> 1) | ((p & 8) >> 1) | (p & 3);
}

// ---------------- kernel 0: repack B,C,D into MFMA A-fragment order ----------------
__global__ void k_prep(const float* __restrict__ Bre, const float* __restrict__ Bim,
                       const float* __restrict__ Cre, const float* __restrict__ Cim,
                       const float* __restrict__ Dm,
                       bf16x8* __restrict__ Bfr, bf16x8* __restrict__ Bfi,
                       bf16x8* __restrict__ Cf, bf16x8* __restrict__ Df) {
  int tid = blockIdx.x * 256 + threadIdx.x;
  int lane = tid & 63, slot = tid >> 6;
  int q = lane >> 4, ln = lane & 15;
  if (slot < 64) {  // B tables
    int ks = slot >> 4, mt = slot & 15;
    int p = mt * 16 + ln;
    bf16x8 vr, vi;
#pragma unroll
    for (int e = 0; e < 8; ++e) {
      int h = ks * 32 + q * 8 + e;
      vr[e] = (short)f2bf(Bre[p * Hd + h]);
      vi[e] = (short)f2bf(Bim[p * Hd + h]);
    }
    Bfr[slot * 64 + lane] = vr;
    Bfi[slot * 64 + lane] = vi;
  } else if (slot < 64 + 128) {  // C table, K' = 512 interleaved (re, -im)
    int s2 = slot - 64;
    int ks = s2 >> 3, mt = s2 & 7;
    int o = mt * 16 + ln;
    bf16x8 v;
#pragma unroll
    for (int e = 0; e < 8; ++e) {
      int kp = ks * 32 + q * 8 + e;
      int p = kp >> 1;
      float val = (kp & 1) ? -Cim[o * Pd + p] : Cre[o * Pd + p];
      v[e] = (short)f2bf(val);
    }
    Cf[s2 * 64 + lane] = v;
  } else if (slot < 64 + 128 + 32) {  // D table
    int s3 = slot - 192;
    int ks = s3 >> 3, mt = s3 & 7;
    int o = mt * 16 + ln;
    bf16x8 v;
#pragma unroll
    for (int e = 0; e < 8; ++e) {
      int h = ks * 32 + q * 8 + e;
      v[e] = (short)f2bf(Dm[o * Hd + h]);
    }
    Df[s3 * 64 + lane] = v;
  }
}

// ---- u staging split: load (global->regs, issued early) / write (regs->LDS) ----
struct ust { float4 a0, a1, b0, b1; };

__device__ __forceinline__ ust stage_load(const float* __restrict__ ub, int t) {
  int lane = t & 63, w = t >> 6;
  int j0 = 4 * (lane & 7);
  int h2 = 16 * w + 2 * (lane >> 3);
  const float* r0 = ub + (size_t)h2 * Ld + j0;
  ust s;
  s.a0 = *(const float4*)r0;
  s.a1 = *(const float4*)(r0 + Ld);
  const float* r2 = r0 + (size_t)64 * Ld;
  s.b0 = *(const float4*)r2;
  s.b1 = *(const float4*)(r2 + Ld);
  return s;
}

__device__ __forceinline__ void stage_write(const ust& s, unsigned* us32, int t) {
  int lane = t & 63, w = t >> 6;
  int j0 = 4 * (lane & 7);
  int h2 = 16 * w + 2 * (lane >> 3);
  float ta0[4] = {s.a0.x, s.a0.y, s.a0.z, s.a0.w};
  float ta1[4] = {s.a1.x, s.a1.y, s.a1.z, s.a1.w};
  float tb0[4] = {s.b0.x, s.b0.y, s.b0.z, s.b0.w};
  float tb1[4] = {s.b1.x, s.b1.y, s.b1.z, s.b1.w};
#pragma unroll
  for (int i = 0; i < 4; ++i) {
    int j = j0 + i;
    int g1 = (h2 >> 3) ^ (j & 7);
    us32[(j * 256 + (g1 << 4) + ((2 * h2) & 15)) >> 2] = pack2(ta0[i], ta1[i]);
    int hb = h2 + 64;
    int g2 = (hb >> 3) ^ (j & 7);
    us32[(j * 256 + (g2 << 4) + ((2 * hb) & 15)) >> 2] = pack2(tb0[i], tb1[i]);
  }
}

// Bu = B_bar @ u_tile via MFMA; writes packed bf16 (re,im) to bu32[p<<5 | (j^perm(p))]
__device__ __forceinline__ void compute_bu(const unsigned* us32,
                                           const bf16x8* __restrict__ Bfr,
                                           const bf16x8* __restrict__ Bfi,
                                           unsigned* bu32, int t) {
  int lane = t & 63, w = t >> 6, q = lane >> 4, ln = lane & 15;
  f32x4 zz = {0.f, 0.f, 0.f, 0.f};
  f32x4 aR[4][2], aI[4][2];
#pragma unroll
  for (int mt = 0; mt < 4; ++mt)
#pragma unroll
    for (int n = 0; n < 2; ++n) { aR[mt][n] = zz; aI[mt][n] = zz; }

#pragma unroll
  for (int ks = 0; ks < 4; ++ks) {
    bf16x8 ubf[2];
#pragma unroll
    for (int n = 0; n < 2; ++n) {
      int j = 16 * n + ln;
      int g = (4 * ks + q) ^ (j & 7);
      ubf[n] = *(const bf16x8*)((const char*)us32 + j * 256 + g * 16);
    }
#pragma unroll
    for (int mt = 0; mt < 4; ++mt) {
      int tI = ks * 16 + w * 4 + mt;
      bf16x8 ar = Bfr[tI * 64 + lane];
      bf16x8 ai = Bfi[tI * 64 + lane];
#pragma unroll
      for (int n = 0; n < 2; ++n) {
        aR[mt][n] = MFMA16(ar, ubf[n], aR[mt][n]);
        aI[mt][n] = MFMA16(ai, ubf[n], aI[mt][n]);
      }
    }
  }
#pragma unroll
  for (int mt = 0; mt < 4; ++mt)
#pragma unroll
    for (int n = 0; n < 2; ++n)
#pragma unroll
      for (int r = 0; r < 4; ++r) {
        int p = w * 64 + mt * 16 + q * 4 + r;
        int j = 16 * n + ln;
        bu32[(p << 5) | (j ^ bperm(p))] = pack2(aR[mt][n][r], aI[mt][n][r]);
      }
}

// thread p reads its bu row -- wave w owns exactly p in [64w, 64w+64), so this
// is a same-wave LDS exchange: NO __syncthreads needed after compute_bu.
__device__ __forceinline__ void capture_v(const unsigned* bu32, unsigned (&v)[LC],
                                          int p, int pm) {
#pragma unroll
  for (int j = 0; j < LC; ++j) v[j] = bu32[(p << 5) | (j ^ pm)];
}

// zero-seeded chunk scan from regs -> xs layout in LDS + chunk total -> E
__device__ __forceinline__ void scan_chunk(unsigned* xs32, float2* __restrict__ E,
                                           const unsigned (&v)[LC], int bc, int p,
                                           float ax, float ay) {
  float xr = 0.f, xi = 0.f;
#pragma unroll
  for (int j = 0; j < LC; ++j) {
    float sr = xr + bflo(v[j]), si = xi + bfhi(v[j]);
    xr = ax * sr - ay * si;
    xi = ax * si + ay * sr;
    xs32[j * 256 + ((((p >> 2) ^ (j & 7)) << 2) + (p & 3))] = pack2(xr, xi);
  }
  E[(size_t)bc * Pd + p] = make_float2(xr, xi);
}

// ---- projection: partial0 = [Cre | -Cim] @ xs0 + D @ u; store packed bf16 ----
__device__ __forceinline__ void projectP(const bf16x8* __restrict__ Cf,
                                         const bf16x8* __restrict__ Df,
                                         const unsigned* us32, const unsigned* xs32,
                                         unsigned* __restrict__ p0out, int bc, int t) {
  int lane = t & 63, w = t >> 6, q = lane >> 4, ln = lane & 15;
  f32x4 zz = {0.f, 0.f, 0.f, 0.f};
  f32x4 acc[2][2] = {{zz, zz}, {zz, zz}};
#pragma unroll
  for (int ks = 0; ks < 16; ++ks) {
    bf16x8 xb[2];
#pragma unroll
    for (int n = 0; n < 2; ++n) {
      int j = 16 * n + ln;
      int g = (4 * ks + q) ^ (j & 7);
      xb[n] = *(const bf16x8*)((const char*)xs32 + j * 1024 + g * 16);
    }
#pragma unroll
    for (int mt = 0; mt < 2; ++mt) {
      bf16x8 cf = Cf[(ks * 8 + w * 2 + mt) * 64 + lane];
#pragma unroll
      for (int n = 0; n < 2; ++n) acc[mt][n] = MFMA16(cf, xb[n], acc[mt][n]);
    }
  }
#pragma unroll
  for (int ks = 0; ks < 4; ++ks) {
    bf16x8 ubf[2];
#pragma unroll
    for (int n = 0; n < 2; ++n) {
      int j = 16 * n + ln;
      int g = (4 * ks + q) ^ (j & 7);
      ubf[n] = *(const bf16x8*)((const char*)us32 + j * 256 + g * 16);
    }
#pragma unroll
    for (int mt = 0; mt < 2; ++mt) {
      bf16x8 df = Df[(ks * 8 + w * 2 + mt) * 64 + lane];
#pragma unroll
      for (int n = 0; n < 2; ++n) acc[mt][n] = MFMA16(df, ubf[n], acc[mt][n]);
    }
  }
  // packed store: one u32 holds (n=0, n=1) bf16 pair
#pragma unroll
  for (int mt = 0; mt < 2; ++mt)
#pragma unroll
    for (int r = 0; r < 4; ++r) {
      int o = w * 32 + mt * 16 + q * 4 + r;
      p0out[(size_t)bc * 2048 + o * 16 + ln] = pack2(acc[mt][0][r], acc[mt][1][r]);
    }
}

// ---------------- kernel 1: 1024 blocks x 2 chunks, software-pipelined ----------------
// All blocks co-resident (4/CU at 40KB LDS). Chunk B's u loads issue before
// chunk A's compute -> HBM/L3 latency hides under Bu MFMAs + scan + projection.
__global__ __launch_bounds__(256, 4) void k_chunkP(
    const float* __restrict__ u, const float* __restrict__ lre,
    const float* __restrict__ lim, const bf16x8* __restrict__ Bfr,
    const bf16x8* __restrict__ Bfi, const bf16x8* __restrict__ Cf,
    const bf16x8* __restrict__ Df, float2* __restrict__ E,
    unsigned* __restrict__ p0out) {
  int blk = blockIdx.x;
  int b = blk >> 7;
  int cA = (blk & 127) * 2;
  int bcA = (b << 8) | cA;
  __shared__ __align__(16) unsigned char smem[8192 + 32768];
  unsigned* us32 = (unsigned*)smem;
  unsigned* bu32 = (unsigned*)(smem + 8192);
  int t = threadIdx.x;
  int p = t, pm = bperm(p);
  float ax = lre[p], ay = lim[p];
  const float* ubase = u + (size_t)b * Hd * Ld;

  ust sA = stage_load(ubase + cA * LC, t);
  stage_write(sA, us32, t);
  __syncthreads();
  ust sB = stage_load(ubase + cA * LC + LC, t);  // issued early, consumed late
  compute_bu(us32, Bfr, Bfi, bu32, t);
  unsigned v[LC];
  capture_v(bu32, v, p, pm);  // same-wave: no barrier
  __syncthreads();            // all captures done before xs aliases bu
  scan_chunk(bu32, E, v, bcA, p, ax, ay);
  __syncthreads();            // xs ready
  projectP(Cf, Df, us32, bu32, p0out, bcA, t);
  __syncthreads();            // proj LDS reads done
  stage_write(sB, us32, t);
  __syncthreads();
  compute_bu(us32, Bfr, Bfi, bu32, t);
  capture_v(bu32, v, p, pm);
  __syncthreads();
  scan_chunk(bu32, E, v, bcA + 1, p, ax, ay);
  __syncthreads();
  projectP(Cf, Df, us32, bu32, p0out, bcA + 1, t);
}

// ---------------- kernel 2: parallel prefix scan over chunks ----------------
__global__ __launch_bounds__(256) void k_scan(const float* __restrict__ lre,
                                              const float* __restrict__ lim,
                                              float2* __restrict__ E) {
  __shared__ float2 arr[32][8];
  int nb = blockIdx.x;  // 0..255
  int t = threadIdx.x;
  int pl = t & 7, rq = t >> 3;  // rq = run index 0..31
  int b = nb >> 5;
  int p = ((nb & 31) << 3) + pl;
  float ax = lre[p], ay = lim[p];
  float mx = ax, my = ay;
#pragma unroll
  for (int k = 0; k < 5; ++k) {  // m = a^32
    float nx = mx * mx - my * my, ny = 2.f * mx * my;
    mx = nx; my = ny;
  }
  size_t base = ((size_t)(b * NC + rq * 8)) * Pd + p;
  float2 pre[8];
  float cr = 0.f, ci = 0.f;
#pragma unroll
  for (int i = 0; i < 8; ++i) {
    float2 e = E[base + (size_t)i * Pd];
    pre[i] = make_float2(cr, ci);
    float nx = mx * cr - my * ci + e.x;
    float ny = mx * ci + my * cr + e.y;
    cr = nx; ci = ny;
  }
  float Mx = mx, My = my;
#pragma unroll
  for (int k = 0; k < 3; ++k) {  // M = m^8
    float nx = Mx * Mx - My * My, ny = 2.f * Mx * My;
    Mx = nx; My = ny;
  }
  float Vx = cr, Vy = ci;
#pragma unroll
  for (int d = 1; d < 32; d <<= 1) {
    arr[rq][pl] = make_float2(Vx, Vy);
    __syncthreads();
    if (rq >= d) {
      float2 pv = arr[rq - d][pl];
      Vx += Mx * pv.x - My * pv.y;
      Vy += Mx * pv.y + My * pv.x;
    }
    __syncthreads();
    float nx = Mx * Mx - My * My, ny = 2.f * Mx * My;
    Mx = nx; My = ny;
  }
  arr[rq][pl] = make_float2(Vx, Vy);
  __syncthreads();
  float Cx = 0.f, Cy = 0.f;
  if (rq > 0) {
    float2 pv = arr[rq - 1][pl];
    Cx = pv.x; Cy = pv.y;
  }
  float tx = 1.f, ty = 0.f;
#pragma unroll
  for (int i = 0; i < 8; ++i) {
    float ox = pre[i].x + tx * Cx - ty * Cy;
    float oy = pre[i].y + tx * Cy + ty * Cx;
    E[base + (size_t)i * Pd] = make_float2(ox, oy);
    float nx = tx * mx - ty * my, ny = tx * my + ty * mx;
    tx = nx; ty = ny;
  }
}

// corr chain: g_j = a^{j+1} X_in, dual even/odd chains (step a^2) -> xs layout
__device__ __forceinline__ void corr_fill(unsigned* xs32, float2 xin, float ax,
                                          float ay, float a2r, float a2i, int p) {
  float g0r = ax * xin.x - ay * xin.y, g0i = ax * xin.y + ay * xin.x;
  float g1r = a2r * xin.x - a2i * xin.y, g1i = a2r * xin.y + a2i * xin.x;
#pragma unroll
  for (int j = 0; j < LC; j += 2) {
    xs32[j * 256 + ((((p >> 2) ^ (j & 7)) << 2) + (p & 3))] = pack2(g0r, g0i);
    int j1 = j + 1;
    xs32[j1 * 256 + ((((p >> 2) ^ (j1 & 7)) << 2) + (p & 3))] = pack2(g1r, g1i);
    float n0r = a2r * g0r - a2i * g0i, n0i = a2r * g0i + a2i * g0r;
    float n1r = a2r * g1r - a2i * g1i, n1i = a2r * g1i + a2i * g1r;
    g0r = n0r; g0i = n0i; g1r = n1r; g1i = n1i;
  }
}

// C' @ corr + partial0 + GELU + store
__device__ __forceinline__ void proj_corr_store(const bf16x8* __restrict__ Cf,
                                                const unsigned* xs32,
                                                const unsigned (&p0)[8],
                                                float* __restrict__ out, int b,
                                                int c, int t) {
  int lane = t & 63, w = t >> 6, q = lane >> 4, ln = lane & 15;
  f32x4 zz = {0.f, 0.f, 0.f, 0.f};
  f32x4 acc[2][2] = {{zz, zz}, {zz, zz}};
#pragma unroll
  for (int ks = 0; ks < 16; ++ks) {
    bf16x8 xb[2];
#pragma unroll
    for (int n = 0; n < 2; ++n) {
      int j = 16 * n + ln;
      int g = (4 * ks + q) ^ (j & 7);
      xb[n] = *(const bf16x8*)((const char*)xs32 + j * 1024 + g * 16);
    }
#pragma unroll
    for (int mt = 0; mt < 2; ++mt) {
      bf16x8 cf = Cf[(ks * 8 + w * 2 + mt) * 64 + lane];
#pragma unroll
      for (int n = 0; n < 2; ++n) acc[mt][n] = MFMA16(cf, xb[n], acc[mt][n]);
    }
  }
#pragma unroll
  for (int mt = 0; mt < 2; ++mt)
#pragma unroll
    for (int n = 0; n < 2; ++n)
#pragma unroll
      for (int r = 0; r < 4; ++r) {
        int o = w * 32 + mt * 16 + q * 4 + r;
        int l = c * LC + 16 * n + ln;
        float pv = n ? bfhi(p0[mt * 4 + r]) : bflo(p0[mt * 4 + r]);
        float vy = acc[mt][n][r] + pv;
        float e2 = __builtin_amdgcn_exp2f(-2.4554670f * vy);  // exp(-1.702 v)
        float gy = vy * __builtin_amdgcn_rcpf(1.0f + e2);
        out[((size_t)(b * Hd + o)) * Ld + l] = gy;
      }
}

// ---------------- kernel 3: seed correction + GELU, 2 chunks/block ----------------
__global__ __launch_bounds__(256, 4) void k_main2(
    const float* __restrict__ lre, const float* __restrict__ lim,
    const bf16x8* __restrict__ Cf, const float2* __restrict__ E,
    const unsigned* __restrict__ p0in, float* __restrict__ out) {
  int blk = blockIdx.x;
  int b = blk >> 7;
  int cA = (blk & 127) * 2;
  int bcA = (b << 8) | cA;
  __shared__ __align__(16) unsigned xs32[LC * 256];  // 32 KB
  int t = threadIdx.x;
  int lane = t & 63, w = t >> 6, q = lane >> 4, ln = lane & 15;
  int p = t;
  float ax = lre[p], ay = lim[p];
  float a2r = ax * ax - ay * ay, a2i = 2.f * ax * ay;

  // hoist loads for BOTH chunks (B's latency hides under A's compute)
  unsigned pA[8], pB[8];
#pragma unroll
  for (int mt = 0; mt < 2; ++mt)
#pragma unroll
    for (int r = 0; r < 4; ++r) {
      int o = w * 32 + mt * 16 + q * 4 + r;
      pA[mt * 4 + r] = p0in[(size_t)bcA * 2048 + o * 16 + ln];
      pB[mt * 4 + r] = p0in[(size_t)(bcA + 1) * 2048 + o * 16 + ln];
    }
  float2 xinA = E[(size_t)bcA * Pd + p];
  float2 xinB = E[(size_t)(bcA + 1) * Pd + p];

  corr_fill(xs32, xinA, ax, ay, a2r, a2i, p);
  __syncthreads();
  proj_corr_store(Cf, xs32, pA, out, b, cA, t);
  __syncthreads();  // MFMA reads of xs done before overwrite
  corr_fill(xs32, xinB, ax, ay, a2r, a2i, p);
  __syncthreads();
  proj_corr_store(Cf, xs32, pB, out, b, cA + 1, t);
}

// ---------------- launch ----------------
extern "C" void kernel_launch(void* const* d_in, const int* in_sizes, int n_in,
                              void* d_out, int out_size, void* d_ws, size_t ws_size,
                              hipStream_t stream) {
  const float* u   = (const float*)d_in[0];
  const float* lre = (const float*)d_in[1];
  const float* lim = (const float*)d_in[2];
  const float* Bre = (const float*)d_in[3];
  const float* Bim = (const float*)d_in[4];
  const float* Cre = (const float*)d_in[5];
  const float* Cim = (const float*)d_in[6];
  const float* Dm  = (const float*)d_in[7];
  float* out = (float*)d_out;

  char* ws = (char*)d_ws;
  bf16x8* Bfr = (bf16x8*)(ws);                  // 64 KB
  bf16x8* Bfi = (bf16x8*)(ws + 65536);          // 64 KB
  bf16x8* Cf  = (bf16x8*)(ws + 131072);         // 128 KB
  bf16x8* Df  = (bf16x8*)(ws + 262144);         // 32 KB
  float2* E   = (float2*)(ws + (1u << 20));     // 4.19 MB
  unsigned* P0 = (unsigned*)(ws + (16u << 20)); // 16.8 MB packed bf16 partials

  k_prep<<<56, 256, 0, stream>>>(Bre, Bim, Cre, Cim, Dm, Bfr, Bfi, Cf, Df);
  k_chunkP<<<1024, 256, 0, stream>>>(u, lre, lim, Bfr, Bfi, Cf, Df, E, P0);
  k_scan<<<256, 256, 0, stream>>>(lre, lim, E);
  k_main2<<<1024, 256, 0, stream>>>(lre, lim, Cf, E, P0, out);
}

// Round 8
// 145.264 us; speedup vs baseline: 1.2884x; 1.2884x over previous
//
#include <hip/hip_runtime.h>
#include <math.h>

#define Bn 8
#define Hd 128
#define Ld 8192
#define Pd 256
#define LC 32
#define NC 256  // Ld / LC

typedef __attribute__((ext_vector_type(8))) short bf16x8;
typedef __attribute__((ext_vector_type(4))) float f32x4;
#define MFMA16(a, b, c) __builtin_amdgcn_mfma_f32_16x16x32_bf16(a, b, c, 0, 0, 0)

__device__ __forceinline__ unsigned short f2bf(float f) {
  unsigned u = __float_as_uint(f);
  u = u + 0x7fffu + ((u >> 16) & 1u);  // round-to-nearest-even
  return (unsigned short)(u >> 16);
}

#if __has_builtin(__builtin_amdgcn_cvt_pk_bf16_f32)
typedef __attribute__((ext_vector_type(2))) __bf16 v2bf_t;
__device__ __forceinline__ unsigned pack2(float a, float b) {
  v2bf_t r = __builtin_amdgcn_cvt_pk_bf16_f32(a, b);  // low = a, high = b
  unsigned u;
  __builtin_memcpy(&u, &r, 4);
  return u;
}
#else
__device__ __forceinline__ unsigned pack2(float a, float b) {
  return (unsigned)f2bf(a) | ((unsigned)f2bf(b) << 16);
}
#endif

__device__ __forceinline__ float bflo(unsigned v) { return __uint_as_float(v << 16); }
__device__ __forceinline__ float bfhi(unsigned v) { return __uint_as_float(v & 0xffff0000u); }

// xs-layout slot for (p, j): word index j*256 + ((p>>2)^(j&7))*4 + (p&3).
// - b128 C-frag stores (4 consecutive r): 8 words/bank = conflict-free min.
// - per-p capture/scan (lanes vary p, fixed j): 2 lanes/bank = free.
// - projection xb reads (16B per lane at group (4ks+q)^(j&7)): unchanged.
__device__ __forceinline__ int xs_idx(int p, int j) {
  return j * 256 + ((((p >> 2) ^ (j & 7)) << 2) | (p & 3));
}

// ---------------- kernel 0: repack B,C,D into MFMA A-fragment order ----------------
__global__ void k_prep(const float* __restrict__ Bre, const float* __restrict__ Bim,
                       const float* __restrict__ Cre, const float* __restrict__ Cim,
                       const float* __restrict__ Dm,
                       bf16x8* __restrict__ Bfr, bf16x8* __restrict__ Bfi,
                       bf16x8* __restrict__ Cf, bf16x8* __restrict__ Df) {
  int tid = blockIdx.x * 256 + threadIdx.x;
  int lane = tid & 63, slot = tid >> 6;
  int q = lane >> 4, ln = lane & 15;
  if (slot < 64) {  // B tables
    int ks = slot >> 4, mt = slot & 15;
    int p = mt * 16 + ln;
    bf16x8 vr, vi;
#pragma unroll
    for (int e = 0; e < 8; ++e) {
      int h = ks * 32 + q * 8 + e;
      vr[e] = (short)f2bf(Bre[p * Hd + h]);
      vi[e] = (short)f2bf(Bim[p * Hd + h]);
    }
    Bfr[slot * 64 + lane] = vr;
    Bfi[slot * 64 + lane] = vi;
  } else if (slot < 64 + 128) {  // C table, K' = 512 interleaved (re, -im)
    int s2 = slot - 64;
    int ks = s2 >> 3, mt = s2 & 7;
    int o = mt * 16 + ln;
    bf16x8 v;
#pragma unroll
    for (int e = 0; e < 8; ++e) {
      int kp = ks * 32 + q * 8 + e;
      int p = kp >> 1;
      float val = (kp & 1) ? -Cim[o * Pd + p] : Cre[o * Pd + p];
      v[e] = (short)f2bf(val);
    }
    Cf[s2 * 64 + lane] = v;
  } else if (slot < 64 + 128 + 32) {  // D table
    int s3 = slot - 192;
    int ks = s3 >> 3, mt = s3 & 7;
    int o = mt * 16 + ln;
    bf16x8 v;
#pragma unroll
    for (int e = 0; e < 8; ++e) {
      int h = ks * 32 + q * 8 + e;
      v[e] = (short)f2bf(Dm[o * Hd + h]);
    }
    Df[s3 * 64 + lane] = v;
  }
}

// ---- u staging: 32 rows (j) x 128 bf16 (h), 256 B/row, XOR-swizzled 16B granules
__device__ __forceinline__ void stage_u(const float* __restrict__ ub, unsigned* us32, int t) {
  int lane = t & 63, w = t >> 6;
  int j0 = 4 * (lane & 7);
  int h2 = 16 * w + 2 * (lane >> 3);
  const float* r0 = ub + (size_t)h2 * Ld + j0;
  float4 a0 = *(const float4*)r0;
  float4 a1 = *(const float4*)(r0 + Ld);
  const float* r2 = r0 + (size_t)64 * Ld;
  float4 b0 = *(const float4*)r2;
  float4 b1 = *(const float4*)(r2 + Ld);
  float ta0[4] = {a0.x, a0.y, a0.z, a0.w};
  float ta1[4] = {a1.x, a1.y, a1.z, a1.w};
  float tb0[4] = {b0.x, b0.y, b0.z, b0.w};
  float tb1[4] = {b1.x, b1.y, b1.z, b1.w};
#pragma unroll
  for (int i = 0; i < 4; ++i) {
    int j = j0 + i;
    int g1 = (h2 >> 3) ^ (j & 7);
    us32[(j * 256 + (g1 << 4) + ((2 * h2) & 15)) >> 2] = pack2(ta0[i], ta1[i]);
    int hb = h2 + 64;
    int g2 = (hb >> 3) ^ (j & 7);
    us32[(j * 256 + (g2 << 4) + ((2 * hb) & 15)) >> 2] = pack2(tb0[i], tb1[i]);
  }
}

// Bu = B_bar @ u_tile via MFMA; stores packed bf16 (re,im) DIRECTLY in the xs
// layout via ds_write_b128: for fixed (mt,n) the 4 acc rows r=0..3 are 4
// consecutive words at group (p0>>2)^(j&7). Wave w covers p in [64w,64w+64)
// for all j -> thread p's later capture is same-wave (no barrier).
__device__ __forceinline__ void compute_bu(const unsigned* us32,
                                           const bf16x8* __restrict__ Bfr,
                                           const bf16x8* __restrict__ Bfi,
                                           unsigned* xs32, int t) {
  int lane = t & 63, w = t >> 6, q = lane >> 4, ln = lane & 15;
  f32x4 zz = {0.f, 0.f, 0.f, 0.f};
  f32x4 aR[4][2], aI[4][2];
#pragma unroll
  for (int mt = 0; mt < 4; ++mt)
#pragma unroll
    for (int n = 0; n < 2; ++n) { aR[mt][n] = zz; aI[mt][n] = zz; }

#pragma unroll
  for (int ks = 0; ks < 4; ++ks) {
    bf16x8 ubf[2];
#pragma unroll
    for (int n = 0; n < 2; ++n) {
      int j = 16 * n + ln;
      int g = (4 * ks + q) ^ (j & 7);
      ubf[n] = *(const bf16x8*)((const char*)us32 + j * 256 + g * 16);
    }
#pragma unroll
    for (int mt = 0; mt < 4; ++mt) {
      int tI = ks * 16 + w * 4 + mt;
      bf16x8 ar = Bfr[tI * 64 + lane];
      bf16x8 ai = Bfi[tI * 64 + lane];
#pragma unroll
      for (int n = 0; n < 2; ++n) {
        aR[mt][n] = MFMA16(ar, ubf[n], aR[mt][n]);
        aI[mt][n] = MFMA16(ai, ubf[n], aI[mt][n]);
      }
    }
  }
#pragma unroll
  for (int mt = 0; mt < 4; ++mt)
#pragma unroll
    for (int n = 0; n < 2; ++n) {
      int p0 = w * 64 + mt * 16 + q * 4;  // p0 % 4 == 0; rows r = 0..3
      int j = 16 * n + ln;
      int g = (p0 >> 2) ^ (j & 7);
      uint4 wv = make_uint4(pack2(aR[mt][n][0], aI[mt][n][0]),
                            pack2(aR[mt][n][1], aI[mt][n][1]),
                            pack2(aR[mt][n][2], aI[mt][n][2]),
                            pack2(aR[mt][n][3], aI[mt][n][3]));
      *(uint4*)(xs32 + j * 256 + g * 4) = wv;  // 16B-aligned b128
    }
}

// ---------------- kernel 1: per-chunk state contribution E ----------------
__global__ __launch_bounds__(256, 4) void k_chunk(
    const float* __restrict__ u, const float* __restrict__ lre,
    const float* __restrict__ lim, const bf16x8* __restrict__ Bfr,
    const bf16x8* __restrict__ Bfi, float2* __restrict__ E) {
  int bc = blockIdx.x;
  int b = bc >> 8, c = bc & 255;
  __shared__ __align__(16) unsigned char smem[8192 + 32768];
  unsigned* us32 = (unsigned*)smem;
  unsigned* xs32 = (unsigned*)(smem + 8192);
  int t = threadIdx.x;

  stage_u(u + (size_t)b * Hd * Ld + c * LC, us32, t);
  __syncthreads();
  compute_bu(us32, Bfr, Bfi, xs32, t);

  // same-wave capture + zero-seeded total (no barrier, no xs rewrite needed)
  int p = t;
  float ax = lre[p], ay = lim[p];
  float xr = 0.f, xi = 0.f;
#pragma unroll
  for (int j = 0; j < LC; ++j) {
    unsigned v = xs32[xs_idx(p, j)];
    float sr = xr + bflo(v), si = xi + bfhi(v);
    xr = ax * sr - ay * si;
    xi = ax * si + ay * sr;
  }
  E[(size_t)bc * Pd + p] = make_float2(xr, xi);
}

// ---------------- kernel 2: parallel prefix scan over chunks ----------------
// 256 blocks; each block owns 8 (b,p)-rows. 32 threads per row, 8 chunks each.
// Lanes 0..7 = consecutive p -> 64B-line-perfect E loads. Cross-run combine via
// LDS Hillis-Steele with uniform level multiplier squared per step.
__global__ __launch_bounds__(256) void k_scan(const float* __restrict__ lre,
                                              const float* __restrict__ lim,
                                              float2* __restrict__ E) {
  __shared__ float2 arr[32][8];
  int nb = blockIdx.x;  // 0..255
  int t = threadIdx.x;
  int pl = t & 7, rq = t >> 3;  // rq = run index 0..31
  int b = nb >> 5;
  int p = ((nb & 31) << 3) + pl;
  float ax = lre[p], ay = lim[p];
  float mx = ax, my = ay;
#pragma unroll
  for (int k = 0; k < 5; ++k) {  // m = a^32
    float nx = mx * mx - my * my, ny = 2.f * mx * my;
    mx = nx; my = ny;
  }
  size_t base = ((size_t)(b * NC + rq * 8)) * Pd + p;
  float2 pre[8];
  float cr = 0.f, ci = 0.f;
#pragma unroll
  for (int i = 0; i < 8; ++i) {
    float2 e = E[base + (size_t)i * Pd];
    pre[i] = make_float2(cr, ci);
    float nx = mx * cr - my * ci + e.x;
    float ny = mx * ci + my * cr + e.y;
    cr = nx; ci = ny;
  }
  float Mx = mx, My = my;
#pragma unroll
  for (int k = 0; k < 3; ++k) {  // M = m^8
    float nx = Mx * Mx - My * My, ny = 2.f * Mx * My;
    Mx = nx; My = ny;
  }
  float Vx = cr, Vy = ci;
#pragma unroll
  for (int d = 1; d < 32; d <<= 1) {
    arr[rq][pl] = make_float2(Vx, Vy);
    __syncthreads();
    if (rq >= d) {
      float2 pv = arr[rq - d][pl];
      Vx += Mx * pv.x - My * pv.y;
      Vy += Mx * pv.y + My * pv.x;
    }
    __syncthreads();
    float nx = Mx * Mx - My * My, ny = 2.f * Mx * My;
    Mx = nx; My = ny;
  }
  arr[rq][pl] = make_float2(Vx, Vy);
  __syncthreads();
  float Cx = 0.f, Cy = 0.f;
  if (rq > 0) {
    float2 pv = arr[rq - 1][pl];
    Cx = pv.x; Cy = pv.y;
  }
  float tx = 1.f, ty = 0.f;
#pragma unroll
  for (int i = 0; i < 8; ++i) {
    float ox = pre[i].x + tx * Cx - ty * Cy;
    float oy = pre[i].y + tx * Cy + ty * Cx;
    E[base + (size_t)i * Pd] = make_float2(ox, oy);
    float nx = tx * mx - ty * my, ny = tx * my + ty * mx;
    tx = nx; ty = ny;
  }
}

// ---------------- kernel 3: main fused kernel (in-place scan, 2 barriers) ----------------
__global__ __launch_bounds__(256, 4) void k_main(
    const float* __restrict__ u, const float* __restrict__ lre,
    const float* __restrict__ lim, const bf16x8* __restrict__ Bfr,
    const bf16x8* __restrict__ Bfi, const bf16x8* __restrict__ Cf,
    const bf16x8* __restrict__ Df, const float2* __restrict__ E,
    float* __restrict__ out) {
  int bc = blockIdx.x;
  int b = bc >> 8, c = bc & 255;
  __shared__ __align__(16) unsigned char smem[8192 + 32768];
  unsigned* us32 = (unsigned*)smem;
  unsigned* xs32 = (unsigned*)(smem + 8192);
  int t = threadIdx.x;
  int lane = t & 63, w = t >> 6, q = lane >> 4, ln = lane & 15;
  int p = t;

  // prefetch seed + multiplier early (consumed after compute_bu)
  float2 xin = E[(size_t)bc * Pd + p];
  float ax = lre[p], ay = lim[p];

  stage_u(u + (size_t)b * Hd * Ld + c * LC, us32, t);
  __syncthreads();
  compute_bu(us32, Bfr, Bfi, xs32, t);

  // same-wave capture + seeded scan, IN-PLACE rewrite (each slot read+written
  // only by thread p, sequentially) -> no alias barrier needed
  {
    float xr = xin.x, xi = xin.y;
#pragma unroll
    for (int j = 0; j < LC; ++j) {
      int idx = xs_idx(p, j);
      unsigned v = xs32[idx];
      float sr = xr + bflo(v), si = xi + bfhi(v);
      xr = ax * sr - ay * si;
      xi = ax * si + ay * sr;
      xs32[idx] = pack2(xr, xi);
    }
  }
  __syncthreads();  // xs (scanned) + us ready for cross-wave MFMA reads

  // ---- projection: y = [Cre | -Cim] @ xs_interleaved + D @ u ----
  f32x4 zz = {0.f, 0.f, 0.f, 0.f};
  f32x4 acc[2][2] = {{zz, zz}, {zz, zz}};
#pragma unroll
  for (int ks = 0; ks < 16; ++ks) {
    bf16x8 xb[2];
#pragma unroll
    for (int n = 0; n < 2; ++n) {
      int j = 16 * n + ln;
      int g = (4 * ks + q) ^ (j & 7);
      xb[n] = *(const bf16x8*)((const char*)xs32 + j * 1024 + g * 16);
    }
#pragma unroll
    for (int mt = 0; mt < 2; ++mt) {
      bf16x8 cf = Cf[(ks * 8 + w * 2 + mt) * 64 + lane];
#pragma unroll
      for (int n = 0; n < 2; ++n) acc[mt][n] = MFMA16(cf, xb[n], acc[mt][n]);
    }
  }
#pragma unroll
  for (int ks = 0; ks < 4; ++ks) {
    bf16x8 ubf[2];
#pragma unroll
    for (int n = 0; n < 2; ++n) {
      int j = 16 * n + ln;
      int g = (4 * ks + q) ^ (j & 7);
      ubf[n] = *(const bf16x8*)((const char*)us32 + j * 256 + g * 16);
    }
#pragma unroll
    for (int mt = 0; mt < 2; ++mt) {
      bf16x8 df = Df[(ks * 8 + w * 2 + mt) * 64 + lane];
#pragma unroll
      for (int n = 0; n < 2; ++n) acc[mt][n] = MFMA16(df, ubf[n], acc[mt][n]);
    }
  }

  // ---- GELU (sigmoid form, |err| <= ~0.02 abs) + store ----
#pragma unroll
  for (int mt = 0; mt < 2; ++mt)
#pragma unroll
    for (int n = 0; n < 2; ++n)
#pragma unroll
      for (int r = 0; r < 4; ++r) {
        int o = w * 32 + mt * 16 + q * 4 + r;
        int l = c * LC + 16 * n + ln;
        float vy = acc[mt][n][r];
        float e2 = __builtin_amdgcn_exp2f(-2.4554670f * vy);  // exp(-1.702 v)
        float gy = vy * __builtin_amdgcn_rcpf(1.0f + e2);
        out[((size_t)(b * Hd + o)) * Ld + l] = gy;
      }
}

// ---------------- launch ----------------
extern "C" void kernel_launch(void* const* d_in, const int* in_sizes, int n_in,
                              void* d_out, int out_size, void* d_ws, size_t ws_size,
                              hipStream_t stream) {
  const float* u   = (const float*)d_in[0];
  const float* lre = (const float*)d_in[1];
  const float* lim = (const float*)d_in[2];
  const float* Bre = (const float*)d_in[3];
  const float* Bim = (const float*)d_in[4];
  const float* Cre = (const float*)d_in[5];
  const float* Cim = (const float*)d_in[6];
  const float* Dm  = (const float*)d_in[7];
  float* out = (float*)d_out;

  char* ws = (char*)d_ws;
  bf16x8* Bfr = (bf16x8*)(ws);                 // 64 KB
  bf16x8* Bfi = (bf16x8*)(ws + 65536);         // 64 KB
  bf16x8* Cf  = (bf16x8*)(ws + 131072);        // 128 KB
  bf16x8* Df  = (bf16x8*)(ws + 262144);        // 32 KB
  float2* E   = (float2*)(ws + (1 << 20));     // 4.19 MB

  k_prep<<<56, 256, 0, stream>>>(Bre, Bim, Cre, Cim, Dm, Bfr, Bfi, Cf, Df);
  k_chunk<<<Bn * NC, 256, 0, stream>>>(u, lre, lim, Bfr, Bfi, E);
  k_scan<<<256, 256, 0, stream>>>(lre, lim, E);
  k_main<<<Bn * NC, 256, 0, stream>>>(u, lre, lim, Bfr, Bfi, Cf, Df, E, out);
}